// Round 1
// baseline (2135.313 us; speedup 1.0000x reference)
//
#include <hip/hip_runtime.h>
#include <math.h>

#define D_IN 128

// ---------------- setup kernels ----------------

__global__ void deg_count_kernel(const int* __restrict__ src, const int* __restrict__ dst,
                                 const float* __restrict__ w, float* __restrict__ deg,
                                 int* __restrict__ cnt, int E) {
    int e = blockIdx.x * blockDim.x + threadIdx.x;
    if (e >= E) return;
    atomicAdd(&deg[src[e]], w[e]);
    atomicAdd(&cnt[dst[e]], 1);
}

__global__ void dinv_kernel(float* __restrict__ deg, int n) {
    int i = blockIdx.x * blockDim.x + threadIdx.x;
    if (i >= n) return;
    float d = deg[i];
    deg[i] = (d > 0.f) ? rsqrtf(d) : 0.f;
}

__global__ void norm_kernel(const int* __restrict__ src, const int* __restrict__ dst,
                            const float* __restrict__ w, const float* __restrict__ dinv,
                            float* __restrict__ norm, int E) {
    int e = blockIdx.x * blockDim.x + threadIdx.x;
    if (e >= E) return;
    norm[e] = dinv[src[e]] * w[e] * dinv[dst[e]];
}

// ---------------- scan (row_ptr build) ----------------
// scan1: inclusive scan of cnt in 1024-element chunks -> incl (= rp+1), block sums -> bsum
__global__ void scan1_kernel(const int* __restrict__ cnt, int* __restrict__ incl,
                             int* __restrict__ bsum, int n) {
    __shared__ int sdata[256];
    int b = blockIdx.x, t = threadIdx.x;
    int base = b * 1024 + t * 4;
    int v[4];
    int s = 0;
#pragma unroll
    for (int k = 0; k < 4; ++k) {
        int idx = base + k;
        v[k] = (idx < n) ? cnt[idx] : 0;
        s += v[k];
    }
    sdata[t] = s;
    __syncthreads();
    for (int off = 1; off < 256; off <<= 1) {
        int y = (t >= off) ? sdata[t - off] : 0;
        __syncthreads();
        sdata[t] += y;
        __syncthreads();
    }
    int run = (t > 0) ? sdata[t - 1] : 0;
#pragma unroll
    for (int k = 0; k < 4; ++k) {
        int idx = base + k;
        run += v[k];
        if (idx < n) incl[idx] = run;
    }
    if (t == 255) bsum[b] = sdata[255];
}

// scan2: single-block inclusive scan of block sums (nb <= 128)
__global__ void scan2_kernel(int* __restrict__ bsum, int nb) {
    __shared__ int sd[128];
    int t = threadIdx.x;
    sd[t] = (t < nb) ? bsum[t] : 0;
    __syncthreads();
    for (int off = 1; off < 128; off <<= 1) {
        int y = (t >= off) ? sd[t - off] : 0;
        __syncthreads();
        sd[t] += y;
        __syncthreads();
    }
    if (t < nb) bsum[t] = sd[t];
}

// scan3: add block offsets; set rp[0] = 0
__global__ void scan3_kernel(int* __restrict__ incl, const int* __restrict__ bsum,
                             int n, int* __restrict__ rp) {
    int b = blockIdx.x, t = threadIdx.x;
    int add = (b > 0) ? bsum[b - 1] : 0;
    int base = b * 1024 + t * 4;
#pragma unroll
    for (int k = 0; k < 4; ++k) {
        int idx = base + k;
        if (idx < n) incl[idx] += add;
    }
    if (b == 0 && t == 0) rp[0] = 0;
}

__global__ void scatter_kernel(const int* __restrict__ src, const int* __restrict__ dst,
                               const float* __restrict__ norm, const int* __restrict__ rp,
                               int* __restrict__ fill, int* __restrict__ col,
                               float* __restrict__ val, int E) {
    int e = blockIdx.x * blockDim.x + threadIdx.x;
    if (e >= E) return;
    int d = dst[e];
    int pos = atomicAdd(&fill[d], 1);
    int o = rp[d] + pos;
    col[o] = src[e];
    val[o] = norm[e];
}

// ---------------- SpMM: out = alpha * (A_csr @ H) + beta * G ----------------
// A_csr holds norm values; Lmul = -A@h so alpha carries the minus sign.
template <int F>
__global__ void spmm_kernel(const float* __restrict__ H, const float* __restrict__ Gm,
                            float* __restrict__ out, const int* __restrict__ rp,
                            const int* __restrict__ col, const float* __restrict__ val,
                            float alpha, float beta, int n) {
    constexpr int RPB = 256 / F;
    int row = blockIdx.x * RPB + threadIdx.x / F;
    if (row >= n) return;
    int f = threadIdx.x & (F - 1);
    float acc = 0.f;
    int e1 = rp[row + 1];
    for (int e = rp[row]; e < e1; ++e) {
        acc += val[e] * H[col[e] * F + f];
    }
    float r = alpha * acc;
    if (beta != 0.f) r += beta * Gm[row * F + f];
    out[row * F + f] = r;
}

// ---------------- dense: out = relu(H0@W0 + T1@W1 + T2@W2 + b) ----------------
template <int F, int G>
__global__ void gemm_relu_kernel(const float* __restrict__ H0, const float* __restrict__ T1,
                                 const float* __restrict__ T2, const float* __restrict__ W,
                                 const float* __restrict__ b, float* __restrict__ out, int n) {
    constexpr int RPB = 256 / G;
    int i = blockIdx.x * RPB + threadIdx.x / G;
    if (i >= n) return;
    int g = threadIdx.x & (G - 1);
    const float* W0 = W;
    const float* W1 = W + F * G;
    const float* W2 = W + 2 * F * G;
    float acc = b[g];
#pragma unroll 4
    for (int f = 0; f < F; ++f) {
        acc = fmaf(H0[i * F + f], W0[f * G + g], acc);
        acc = fmaf(T1[i * F + f], W1[f * G + g], acc);
        acc = fmaf(T2[i * F + f], W2[f * G + g], acc);
    }
    out[i * G + g] = fmaxf(acc, 0.f);
}

// ---------------- final layer: F=16 -> 4 logits -> log_softmax ----------------
__global__ void layer4_kernel(const float* __restrict__ H0, const float* __restrict__ T1,
                              const float* __restrict__ T2, const float* __restrict__ W,
                              const float* __restrict__ b, float* __restrict__ out, int n) {
    int i = blockIdx.x * blockDim.x + threadIdx.x;
    if (i >= n) return;
    float o[4];
#pragma unroll
    for (int g = 0; g < 4; ++g) o[g] = b[g];
    const float* W0 = W;
    const float* W1 = W + 16 * 4;
    const float* W2 = W + 2 * 16 * 4;
#pragma unroll
    for (int f = 0; f < 16; ++f) {
        float h = H0[i * 16 + f], t1 = T1[i * 16 + f], t2 = T2[i * 16 + f];
#pragma unroll
        for (int g = 0; g < 4; ++g) {
            o[g] = fmaf(h, W0[f * 4 + g], o[g]);
            o[g] = fmaf(t1, W1[f * 4 + g], o[g]);
            o[g] = fmaf(t2, W2[f * 4 + g], o[g]);
        }
    }
    float m = fmaxf(fmaxf(o[0], o[1]), fmaxf(o[2], o[3]));
    float s = expf(o[0] - m) + expf(o[1] - m) + expf(o[2] - m) + expf(o[3] - m);
    float ls = m + logf(s);
#pragma unroll
    for (int g = 0; g < 4; ++g) out[i * 4 + g] = o[g] - ls;
}

// ---------------- launch ----------------

extern "C" void kernel_launch(void* const* d_in, const int* in_sizes, int n_in,
                              void* d_out, int out_size, void* d_ws, size_t ws_size,
                              hipStream_t stream) {
    const float* x = (const float*)d_in[0];
    const int* ei = (const int*)d_in[1];
    const float* ew = (const float*)d_in[2];
    const float* W1 = (const float*)d_in[3];
    const float* b1 = (const float*)d_in[4];
    const float* W2 = (const float*)d_in[5];
    const float* b2 = (const float*)d_in[6];
    const float* W3 = (const float*)d_in[7];
    const float* b3 = (const float*)d_in[8];
    const float* W4 = (const float*)d_in[9];
    const float* b4 = (const float*)d_in[10];
    float* out = (float*)d_out;

    const int n = in_sizes[0] / D_IN;   // 100000
    const int E = in_sizes[2];          // 1600000
    const int* src = ei;
    const int* dst = ei + E;

    // workspace layout (all 4-byte elements)
    char* p = (char*)d_ws;
    float* deg = (float*)p;            p += (size_t)n * 4;
    float* norm = (float*)p;           p += (size_t)E * 4;
    int* cnt = (int*)p;                p += (size_t)n * 4;   // counts, then fill cursors
    int* rp = (int*)p;                 p += (size_t)(n + 1) * 4;
    int* bsum = (int*)p;               p += 128 * 4;
    int* col = (int*)p;                p += (size_t)E * 4;
    float* val = (float*)p;            p += (size_t)E * 4;
    float* T1 = (float*)p;             p += (size_t)n * 128 * 4;
    float* T2 = (float*)p;             p += (size_t)n * 128 * 4;
    float* H1 = (float*)p;             p += (size_t)n * 64 * 4;
    float* H2 = (float*)p;             p += (size_t)n * 32 * 4;
    float* H3 = (float*)p;             p += (size_t)n * 16 * 4;

    const int TB = 256;
    int eb = (E + TB - 1) / TB;
    int nb256 = (n + TB - 1) / TB;
    int nscan = (n + 1023) / 1024;

    // ---- graph normalization + CSR build ----
    hipMemsetAsync(deg, 0, (size_t)n * 4, stream);
    hipMemsetAsync(cnt, 0, (size_t)n * 4, stream);
    deg_count_kernel<<<eb, TB, 0, stream>>>(src, dst, ew, deg, cnt, E);
    dinv_kernel<<<nb256, TB, 0, stream>>>(deg, n);
    norm_kernel<<<eb, TB, 0, stream>>>(src, dst, ew, deg, norm, E);
    scan1_kernel<<<nscan, 256, 0, stream>>>(cnt, rp + 1, bsum, n);
    scan2_kernel<<<1, 128, 0, stream>>>(bsum, nscan);
    scan3_kernel<<<nscan, 256, 0, stream>>>(rp + 1, bsum, n, rp);
    hipMemsetAsync(cnt, 0, (size_t)n * 4, stream);  // reuse as fill cursors
    scatter_kernel<<<eb, TB, 0, stream>>>(src, dst, norm, rp, cnt, col, val, E);

    // ---- layer 1: F=128 -> 64 ----
    {
        constexpr int F = 128;
        int blocks = (n * F + 255) / 256;
        spmm_kernel<F><<<blocks, 256, 0, stream>>>(x, nullptr, T1, rp, col, val, -1.f, 0.f, n);
        spmm_kernel<F><<<blocks, 256, 0, stream>>>(T1, x, T2, rp, col, val, -2.f, -1.f, n);
        constexpr int G = 64;
        int gblocks = (n * G + 255) / 256;
        gemm_relu_kernel<F, G><<<gblocks, 256, 0, stream>>>(x, T1, T2, W1, b1, H1, n);
    }
    // ---- layer 2: F=64 -> 32 ----
    {
        constexpr int F = 64;
        int blocks = (n * F + 255) / 256;
        spmm_kernel<F><<<blocks, 256, 0, stream>>>(H1, nullptr, T1, rp, col, val, -1.f, 0.f, n);
        spmm_kernel<F><<<blocks, 256, 0, stream>>>(T1, H1, T2, rp, col, val, -2.f, -1.f, n);
        constexpr int G = 32;
        int gblocks = (n * G + 255) / 256;
        gemm_relu_kernel<F, G><<<gblocks, 256, 0, stream>>>(H1, T1, T2, W2, b2, H2, n);
    }
    // ---- layer 3: F=32 -> 16 ----
    {
        constexpr int F = 32;
        int blocks = (n * F + 255) / 256;
        spmm_kernel<F><<<blocks, 256, 0, stream>>>(H2, nullptr, T1, rp, col, val, -1.f, 0.f, n);
        spmm_kernel<F><<<blocks, 256, 0, stream>>>(T1, H2, T2, rp, col, val, -2.f, -1.f, n);
        constexpr int G = 16;
        int gblocks = (n * G + 255) / 256;
        gemm_relu_kernel<F, G><<<gblocks, 256, 0, stream>>>(H2, T1, T2, W3, b3, H3, n);
    }
    // ---- layer 4: F=16 -> 4, log_softmax ----
    {
        constexpr int F = 16;
        int blocks = (n * F + 255) / 256;
        spmm_kernel<F><<<blocks, 256, 0, stream>>>(H3, nullptr, T1, rp, col, val, -1.f, 0.f, n);
        spmm_kernel<F><<<blocks, 256, 0, stream>>>(T1, H3, T2, rp, col, val, -2.f, -1.f, n);
        layer4_kernel<<<nb256, TB, 0, stream>>>(H3, T1, T2, W4, b4, out, n);
    }
}

// Round 2
// 1068.786 us; speedup vs baseline: 1.9979x; 1.9979x over previous
//
#include <hip/hip_runtime.h>
#include <math.h>

#define D_IN 128

// ---------------- setup kernels ----------------

__global__ void deg_count_kernel(const int* __restrict__ src, const int* __restrict__ dst,
                                 const float* __restrict__ w, float* __restrict__ deg,
                                 int* __restrict__ cnt, int E) {
    int e = blockIdx.x * blockDim.x + threadIdx.x;
    if (e >= E) return;
    atomicAdd(&deg[src[e]], w[e]);
    atomicAdd(&cnt[dst[e]], 1);
}

__global__ void dinv_kernel(float* __restrict__ deg, int n) {
    int i = blockIdx.x * blockDim.x + threadIdx.x;
    if (i >= n) return;
    float d = deg[i];
    deg[i] = (d > 0.f) ? rsqrtf(d) : 0.f;
}

// ---------------- scan (row_ptr build) ----------------
__global__ void scan1_kernel(const int* __restrict__ cnt, int* __restrict__ incl,
                             int* __restrict__ bsum, int n) {
    __shared__ int sdata[256];
    int b = blockIdx.x, t = threadIdx.x;
    int base = b * 1024 + t * 4;
    int v[4];
    int s = 0;
#pragma unroll
    for (int k = 0; k < 4; ++k) {
        int idx = base + k;
        v[k] = (idx < n) ? cnt[idx] : 0;
        s += v[k];
    }
    sdata[t] = s;
    __syncthreads();
    for (int off = 1; off < 256; off <<= 1) {
        int y = (t >= off) ? sdata[t - off] : 0;
        __syncthreads();
        sdata[t] += y;
        __syncthreads();
    }
    int run = (t > 0) ? sdata[t - 1] : 0;
#pragma unroll
    for (int k = 0; k < 4; ++k) {
        int idx = base + k;
        run += v[k];
        if (idx < n) incl[idx] = run;
    }
    if (t == 255) bsum[b] = sdata[255];
}

__global__ void scan2_kernel(int* __restrict__ bsum, int nb) {
    __shared__ int sd[128];
    int t = threadIdx.x;
    sd[t] = (t < nb) ? bsum[t] : 0;
    __syncthreads();
    for (int off = 1; off < 128; off <<= 1) {
        int y = (t >= off) ? sd[t - off] : 0;
        __syncthreads();
        sd[t] += y;
        __syncthreads();
    }
    if (t < nb) bsum[t] = sd[t];
}

__global__ void scan3_kernel(int* __restrict__ incl, const int* __restrict__ bsum,
                             int n, int* __restrict__ rp) {
    int b = blockIdx.x, t = threadIdx.x;
    int add = (b > 0) ? bsum[b - 1] : 0;
    int base = b * 1024 + t * 4;
#pragma unroll
    for (int k = 0; k < 4; ++k) {
        int idx = base + k;
        if (idx < n) incl[idx] += add;
    }
    if (b == 0 && t == 0) rp[0] = 0;
}

// scatter with fused norm computation; writes packed (col, val)
__global__ void scatter_kernel(const int* __restrict__ src, const int* __restrict__ dst,
                               const float* __restrict__ w, const float* __restrict__ dinv,
                               const int* __restrict__ rp, int* __restrict__ fill,
                               int2* __restrict__ cv, int E) {
    int e = blockIdx.x * blockDim.x + threadIdx.x;
    if (e >= E) return;
    int s = src[e], d = dst[e];
    float v = dinv[s] * w[e] * dinv[d];
    int pos = atomicAdd(&fill[d], 1);
    int o = rp[d] + pos;
    int2 c;
    c.x = s;
    c.y = __float_as_int(v);
    cv[o] = c;
}

// ---------------- Wcat: Wc[f][0:G)=W0-W2, [G:2G)=W1, [2G:3G)=W2 ----------------
__global__ void wcat_kernel(const float* __restrict__ W, float* __restrict__ Wc, int F, int G) {
    int i = blockIdx.x * blockDim.x + threadIdx.x;
    int NC = 3 * G;
    if (i >= F * NC) return;
    int f = i / NC, c = i % NC;
    float v;
    if (c < G) v = W[f * G + c] - W[2 * F * G + f * G + c];
    else if (c < 2 * G) v = W[F * G + f * G + (c - G)];
    else v = W[2 * F * G + f * G + (c - 2 * G)];
    Wc[i] = v;
}

// ---------------- tiled GEMM: Y[n,NC] = H[n,F] @ Wc[F,NC] ----------------
// BM=256 rows/block, NCT cols/block-tile, 256 threads, per-thread 8 rows x CPT cols.
template <int F, int NC, int NCT, int BK>
__global__ __launch_bounds__(256, 3) void gemm_tiled(const float* __restrict__ H,
                                                     const float* __restrict__ Wc,
                                                     float* __restrict__ Y, int n) {
    constexpr int CPT = NCT / 8;
    constexpr int KSTEPS = F / BK;
    __shared__ float Hs[BK][256];
    __shared__ float Ws[BK][NCT];

    const int tid = threadIdx.x;
    const int rowBase = blockIdx.x * 256;
    const int ct = blockIdx.y * NCT;

    const int rg = tid & 31;
    const int cg = tid >> 5;  // 0..7
    const int c0 = cg * CPT;

    float acc[8][CPT];
#pragma unroll
    for (int i = 0; i < 8; ++i)
#pragma unroll
        for (int c = 0; c < CPT; ++c) acc[i][c] = 0.f;

    int gr = rowBase + tid;
    if (gr >= n) gr = n - 1;
    const float* Hrow = H + (size_t)gr * F;

    for (int ks = 0; ks < KSTEPS; ++ks) {
        const int k0 = ks * BK;
        // stage H tile transposed: Hs[k][localRow]
#pragma unroll
        for (int j = 0; j < BK / 4; ++j) {
            float4 hv = *(const float4*)(Hrow + k0 + j * 4);
            Hs[j * 4 + 0][tid] = hv.x;
            Hs[j * 4 + 1][tid] = hv.y;
            Hs[j * 4 + 2][tid] = hv.z;
            Hs[j * 4 + 3][tid] = hv.w;
        }
        // stage W tile
        constexpr int WTOT = BK * NCT;
#pragma unroll
        for (int j = 0; j < WTOT / 256; ++j) {
            int idx = tid + j * 256;
            int k = idx / NCT, c = idx % NCT;
            Ws[k][c] = Wc[(size_t)(k0 + k) * NC + ct + c];
        }
        __syncthreads();
#pragma unroll
        for (int kk = 0; kk < BK; ++kk) {
            float4 ha = *(const float4*)&Hs[kk][rg * 4];
            float4 hb = *(const float4*)&Hs[kk][128 + rg * 4];
            float h[8] = {ha.x, ha.y, ha.z, ha.w, hb.x, hb.y, hb.z, hb.w};
            float w[CPT];
            if constexpr (CPT % 4 == 0) {
#pragma unroll
                for (int c4 = 0; c4 < CPT / 4; ++c4) {
                    float4 wv = *(const float4*)&Ws[kk][c0 + c4 * 4];
                    w[c4 * 4 + 0] = wv.x;
                    w[c4 * 4 + 1] = wv.y;
                    w[c4 * 4 + 2] = wv.z;
                    w[c4 * 4 + 3] = wv.w;
                }
            } else {
#pragma unroll
                for (int c2 = 0; c2 < CPT / 2; ++c2) {
                    float2 wv = *(const float2*)&Ws[kk][c0 + c2 * 2];
                    w[c2 * 2 + 0] = wv.x;
                    w[c2 * 2 + 1] = wv.y;
                }
            }
#pragma unroll
            for (int i = 0; i < 8; ++i)
#pragma unroll
                for (int c = 0; c < CPT; ++c) acc[i][c] = fmaf(h[i], w[c], acc[i][c]);
        }
        __syncthreads();
    }
    // store: rows rg*4 + {0..3} and 128 + rg*4 + {0..3}
#pragma unroll
    for (int half = 0; half < 2; ++half) {
#pragma unroll
        for (int i = 0; i < 4; ++i) {
            int r = rowBase + half * 128 + rg * 4 + i;
            if (r < n) {
                float* dstp = Y + (size_t)r * NC + ct + c0;
#pragma unroll
                for (int c = 0; c < CPT; ++c) dstp[c] = acc[half * 4 + i][c];
            }
        }
    }
}

// ---------------- small GEMM for layer 4: [n,16] @ [16,12] ----------------
__global__ void gemm_small(const float* __restrict__ H, const float* __restrict__ Wc,
                           float* __restrict__ Y, int n) {
    __shared__ float Ws[16 * 12];
    if (threadIdx.x < 192) Ws[threadIdx.x] = Wc[threadIdx.x];
    __syncthreads();
    int i = blockIdx.x * blockDim.x + threadIdx.x;
    if (i >= n) return;
    const float* h = H + (size_t)i * 16;
    float acc[12];
#pragma unroll
    for (int g = 0; g < 12; ++g) acc[g] = 0.f;
#pragma unroll
    for (int j = 0; j < 4; ++j) {
        float4 hv = *(const float4*)(h + j * 4);
        float hf[4] = {hv.x, hv.y, hv.z, hv.w};
#pragma unroll
        for (int k = 0; k < 4; ++k) {
            int f = j * 4 + k;
#pragma unroll
            for (int g = 0; g < 12; ++g) acc[g] = fmaf(hf[k], Ws[f * 12 + g], acc[g]);
        }
    }
    float* dstp = Y + (size_t)i * 12;
#pragma unroll
    for (int g = 0; g < 12; ++g) dstp[g] = acc[g];
}

// ---------------- SpMM: out[n,G] = alpha*(A@Hsrc) [+ beta*Gm] [+bias, relu] ----------------
template <int G, int MODE>  // MODE 0: alpha only; 1: +beta*Gm; 2: +beta*Gm + bias + relu
__global__ void spmm(const float* __restrict__ H, int ldH, int offH,
                     const float* __restrict__ Gm, int ldGm, int offGm,
                     const float* __restrict__ bias, float* __restrict__ out,
                     const int2* __restrict__ cv, const int* __restrict__ rp,
                     float alpha, float beta, int n) {
    constexpr int TPR = G / 2;
    constexpr int RPB = 256 / TPR;
    int row = blockIdx.x * RPB + threadIdx.x / TPR;
    if (row >= n) return;
    int g2 = (threadIdx.x % TPR) * 2;
    float ax = 0.f, ay = 0.f;
    int e0 = rp[row], e1 = rp[row + 1];
    for (int e = e0; e < e1; ++e) {
        int2 c = cv[e];
        float v = __int_as_float(c.y);
        float2 hv = *(const float2*)(H + (size_t)c.x * ldH + offH + g2);
        ax = fmaf(v, hv.x, ax);
        ay = fmaf(v, hv.y, ay);
    }
    float rx = alpha * ax, ry = alpha * ay;
    if (MODE >= 1) {
        const float* gp = Gm + (size_t)row * ldGm + offGm + g2;
        rx = fmaf(beta, gp[0], rx);
        ry = fmaf(beta, gp[1], ry);
    }
    if (MODE == 2) {
        rx = fmaxf(rx + bias[g2], 0.f);
        ry = fmaxf(ry + bias[g2 + 1], 0.f);
    }
    float2 r;
    r.x = rx;
    r.y = ry;
    *(float2*)(out + (size_t)row * G + g2) = r;
}

// ---------------- final: out = log_softmax(Y_A - A@S + b) ----------------
__global__ void layer4_final(const float* __restrict__ S, const float* __restrict__ Y,
                             const float* __restrict__ b, float* __restrict__ out,
                             const int2* __restrict__ cv, const int* __restrict__ rp, int n) {
    int row = blockIdx.x * blockDim.x + threadIdx.x;
    if (row >= n) return;
    float a0 = 0.f, a1 = 0.f, a2 = 0.f, a3 = 0.f;
    int e0 = rp[row], e1 = rp[row + 1];
    for (int e = e0; e < e1; ++e) {
        int2 c = cv[e];
        float v = __int_as_float(c.y);
        float4 sv = *(const float4*)(S + (size_t)c.x * 4);
        a0 = fmaf(v, sv.x, a0);
        a1 = fmaf(v, sv.y, a1);
        a2 = fmaf(v, sv.z, a2);
        a3 = fmaf(v, sv.w, a3);
    }
    const float* ya = Y + (size_t)row * 12;
    float o0 = ya[0] - a0 + b[0];
    float o1 = ya[1] - a1 + b[1];
    float o2 = ya[2] - a2 + b[2];
    float o3 = ya[3] - a3 + b[3];
    float m = fmaxf(fmaxf(o0, o1), fmaxf(o2, o3));
    float s = expf(o0 - m) + expf(o1 - m) + expf(o2 - m) + expf(o3 - m);
    float ls = m + logf(s);
    float4 r;
    r.x = o0 - ls;
    r.y = o1 - ls;
    r.z = o2 - ls;
    r.w = o3 - ls;
    *(float4*)(out + (size_t)row * 4) = r;
}

// ---------------- launch ----------------

static inline char* align_up(char* p, size_t a) {
    return (char*)(((uintptr_t)p + a - 1) & ~(uintptr_t)(a - 1));
}

extern "C" void kernel_launch(void* const* d_in, const int* in_sizes, int n_in,
                              void* d_out, int out_size, void* d_ws, size_t ws_size,
                              hipStream_t stream) {
    const float* x = (const float*)d_in[0];
    const int* ei = (const int*)d_in[1];
    const float* ew = (const float*)d_in[2];
    const float* W1 = (const float*)d_in[3];
    const float* b1 = (const float*)d_in[4];
    const float* W2 = (const float*)d_in[5];
    const float* b2 = (const float*)d_in[6];
    const float* W3 = (const float*)d_in[7];
    const float* b3 = (const float*)d_in[8];
    const float* W4 = (const float*)d_in[9];
    const float* b4 = (const float*)d_in[10];
    float* out = (float*)d_out;

    const int n = in_sizes[0] / D_IN;  // 100000
    const int E = in_sizes[2];         // 1600000
    const int* src = ei;
    const int* dst = ei + E;

    // workspace layout
    char* p = (char*)d_ws;
    int2* cv = (int2*)p;      p += (size_t)E * 8;
    float* deg = (float*)p;   p += (size_t)n * 4;
    int* cnt = (int*)p;       p += (size_t)n * 4;
    int* rp = (int*)p;        p = align_up(p + (size_t)(n + 1) * 4, 64);
    int* bsum = (int*)p;      p = align_up(p + 512, 64);
    float* Wc = (float*)p;    p = align_up(p + 128 * 192 * 4, 64);
    float* Y = (float*)p;     p = align_up(p + (size_t)n * 192 * 4, 64);
    float* S = (float*)p;     p = align_up(p + (size_t)n * 64 * 4, 64);
    float* H1 = (float*)p;    p = align_up(p + (size_t)n * 64 * 4, 64);
    float* H2 = (float*)p;    p = align_up(p + (size_t)n * 32 * 4, 64);
    float* H3 = (float*)p;    p = align_up(p + (size_t)n * 16 * 4, 64);

    const int TB = 256;
    int eb = (E + TB - 1) / TB;
    int nb256 = (n + TB - 1) / TB;
    int nscan = (n + 1023) / 1024;

    // ---- graph normalization + CSR build ----
    hipMemsetAsync(deg, 0, (size_t)n * 4, stream);
    hipMemsetAsync(cnt, 0, (size_t)n * 4, stream);
    deg_count_kernel<<<eb, TB, 0, stream>>>(src, dst, ew, deg, cnt, E);
    dinv_kernel<<<nb256, TB, 0, stream>>>(deg, n);
    scan1_kernel<<<nscan, 256, 0, stream>>>(cnt, rp + 1, bsum, n);
    scan2_kernel<<<1, 128, 0, stream>>>(bsum, nscan);
    scan3_kernel<<<nscan, 256, 0, stream>>>(rp + 1, bsum, n, rp);
    hipMemsetAsync(cnt, 0, (size_t)n * 4, stream);
    scatter_kernel<<<eb, TB, 0, stream>>>(src, dst, ew, deg, rp, cnt, cv, E);

    // ---- layer 1: F=128, G=64 ----
    {
        constexpr int F = 128, G = 64, NC = 192;
        wcat_kernel<<<(F * NC + 255) / 256, 256, 0, stream>>>(W1, Wc, F, G);
        dim3 gg((n + 255) / 256, NC / 96);
        gemm_tiled<F, NC, 96, 32><<<gg, 256, 0, stream>>>(x, Wc, Y, n);
        int sb = (n + (512 / G) - 1) / (512 / G);
        // S = Y_B + 2*L(Y_C) = -2*A@Y_C + Y_B
        spmm<G, 1><<<sb, 256, 0, stream>>>(Y, NC, 2 * G, Y, NC, G, nullptr, S, cv, rp, -2.f, 1.f, n);
        // H1 = relu(Y_A - A@S + b1)
        spmm<G, 2><<<sb, 256, 0, stream>>>(S, G, 0, Y, NC, 0, b1, H1, cv, rp, -1.f, 1.f, n);
    }
    // ---- layer 2: F=64, G=32 ----
    {
        constexpr int F = 64, G = 32, NC = 96;
        wcat_kernel<<<(F * NC + 255) / 256, 256, 0, stream>>>(W2, Wc, F, G);
        dim3 gg((n + 255) / 256, 1);
        gemm_tiled<F, NC, 96, 32><<<gg, 256, 0, stream>>>(H1, Wc, Y, n);
        int sb = (n + (512 / G) - 1) / (512 / G);
        spmm<G, 1><<<sb, 256, 0, stream>>>(Y, NC, 2 * G, Y, NC, G, nullptr, S, cv, rp, -2.f, 1.f, n);
        spmm<G, 2><<<sb, 256, 0, stream>>>(S, G, 0, Y, NC, 0, b2, H2, cv, rp, -1.f, 1.f, n);
    }
    // ---- layer 3: F=32, G=16 ----
    {
        constexpr int F = 32, G = 16, NC = 48;
        wcat_kernel<<<(F * NC + 255) / 256, 256, 0, stream>>>(W3, Wc, F, G);
        dim3 gg((n + 255) / 256, 1);
        gemm_tiled<F, NC, 48, 32><<<gg, 256, 0, stream>>>(H2, Wc, Y, n);
        int sb = (n + (512 / G) - 1) / (512 / G);
        spmm<G, 1><<<sb, 256, 0, stream>>>(Y, NC, 2 * G, Y, NC, G, nullptr, S, cv, rp, -2.f, 1.f, n);
        spmm<G, 2><<<sb, 256, 0, stream>>>(S, G, 0, Y, NC, 0, b3, H3, cv, rp, -1.f, 1.f, n);
    }
    // ---- layer 4: F=16, G=4, log_softmax ----
    {
        constexpr int G = 4, NC = 12;
        wcat_kernel<<<(16 * NC + 255) / 256, 256, 0, stream>>>(W4, Wc, 16, G);
        gemm_small<<<nb256, 256, 0, stream>>>(H3, Wc, Y, n);
        int sb = (n + (512 / G) - 1) / (512 / G);
        spmm<G, 1><<<sb, 256, 0, stream>>>(Y, NC, 2 * G, Y, NC, G, nullptr, S, cv, rp, -2.f, 1.f, n);
        layer4_final<<<nb256, 256, 0, stream>>>(S, Y, b4, out, cv, rp, n);
    }
}

// Round 3
// 701.626 us; speedup vs baseline: 3.0434x; 1.5233x over previous
//
#include <hip/hip_runtime.h>
#include <math.h>

#define D_IN 128
typedef unsigned short ushort_t;

__device__ __forceinline__ float bf2f(ushort_t u) {
    union { unsigned i; float f; } x;
    x.i = ((unsigned)u) << 16;
    return x.f;
}
__device__ __forceinline__ ushort_t f2bf(float f) {
    unsigned i = __float_as_uint(f);
    unsigned r = (i + 0x7fffu + ((i >> 16) & 1u)) >> 16;
    return (ushort_t)r;
}

// ---------------- setup kernels ----------------

__global__ void deg_count_kernel(const int* __restrict__ src, const int* __restrict__ dst,
                                 const float* __restrict__ w, float* __restrict__ deg,
                                 int* __restrict__ cnt, int E) {
    int e = blockIdx.x * blockDim.x + threadIdx.x;
    if (e >= E) return;
    atomicAdd(&deg[src[e]], w[e]);
    atomicAdd(&cnt[dst[e]], 1);
}

__global__ void dinv_kernel(float* __restrict__ deg, int n) {
    int i = blockIdx.x * blockDim.x + threadIdx.x;
    if (i >= n) return;
    float d = deg[i];
    deg[i] = (d > 0.f) ? rsqrtf(d) : 0.f;
}

__global__ void scan1_kernel(const int* __restrict__ cnt, int* __restrict__ incl,
                             int* __restrict__ bsum, int n) {
    __shared__ int sdata[256];
    int b = blockIdx.x, t = threadIdx.x;
    int base = b * 1024 + t * 4;
    int v[4];
    int s = 0;
#pragma unroll
    for (int k = 0; k < 4; ++k) {
        int idx = base + k;
        v[k] = (idx < n) ? cnt[idx] : 0;
        s += v[k];
    }
    sdata[t] = s;
    __syncthreads();
    for (int off = 1; off < 256; off <<= 1) {
        int y = (t >= off) ? sdata[t - off] : 0;
        __syncthreads();
        sdata[t] += y;
        __syncthreads();
    }
    int run = (t > 0) ? sdata[t - 1] : 0;
#pragma unroll
    for (int k = 0; k < 4; ++k) {
        int idx = base + k;
        run += v[k];
        if (idx < n) incl[idx] = run;
    }
    if (t == 255) bsum[b] = sdata[255];
}

__global__ void scan2_kernel(int* __restrict__ bsum, int nb) {
    __shared__ int sd[128];
    int t = threadIdx.x;
    sd[t] = (t < nb) ? bsum[t] : 0;
    __syncthreads();
    for (int off = 1; off < 128; off <<= 1) {
        int y = (t >= off) ? sd[t - off] : 0;
        __syncthreads();
        sd[t] += y;
        __syncthreads();
    }
    if (t < nb) bsum[t] = sd[t];
}

__global__ void scan3_kernel(int* __restrict__ incl, const int* __restrict__ bsum,
                             int n, int* __restrict__ rp) {
    int b = blockIdx.x, t = threadIdx.x;
    int add = (b > 0) ? bsum[b - 1] : 0;
    int base = b * 1024 + t * 4;
#pragma unroll
    for (int k = 0; k < 4; ++k) {
        int idx = base + k;
        if (idx < n) incl[idx] += add;
    }
    if (b == 0 && t == 0) rp[0] = 0;
}

__global__ void scatter_kernel(const int* __restrict__ src, const int* __restrict__ dst,
                               const float* __restrict__ w, const float* __restrict__ dinv,
                               const int* __restrict__ rp, int* __restrict__ fill,
                               int2* __restrict__ cv, int E) {
    int e = blockIdx.x * blockDim.x + threadIdx.x;
    if (e >= E) return;
    int s = src[e], d = dst[e];
    float v = dinv[s] * w[e] * dinv[d];
    int pos = atomicAdd(&fill[d], 1);
    int o = rp[d] + pos;
    int2 c;
    c.x = s;
    c.y = __float_as_int(v);
    cv[o] = c;
}

// ---------------- gemm3: per y-block m: m=0 -> YA=H@(W0-W2), m=1 -> YB=H@W1,
//                  m=2 -> C16=bf16(H@W2).  W layout [3][F][G]. ----------------
template <int F, int G>
__global__ __launch_bounds__(256) void gemm3(const float* __restrict__ H,
                                             const float* __restrict__ W,
                                             float* __restrict__ YA, float* __restrict__ YB,
                                             ushort_t* __restrict__ C16, int n) {
    constexpr int BK = 32;
    constexpr int CPT = G / 8;
    constexpr int KSTEPS = F / BK;
    __shared__ float Hs[BK][256];
    __shared__ float Ws[BK][G];

    const int tid = threadIdx.x;
    const int rowBase = blockIdx.x * 256;
    const int m = blockIdx.y;  // 0,1,2

    const int rg = tid & 31;
    const int cg = tid >> 5;
    const int c0 = cg * CPT;

    float acc[8][CPT];
#pragma unroll
    for (int i = 0; i < 8; ++i)
#pragma unroll
        for (int c = 0; c < CPT; ++c) acc[i][c] = 0.f;

    int gr = rowBase + tid;
    if (gr >= n) gr = n - 1;
    const float* Hrow = H + (size_t)gr * F;

    const float* W0 = W;
    const float* W2 = W + 2 * F * G;
    const float* Wm = W + (size_t)m * F * G;

    for (int ks = 0; ks < KSTEPS; ++ks) {
        const int k0 = ks * BK;
#pragma unroll
        for (int j = 0; j < BK / 4; ++j) {
            float4 hv = *(const float4*)(Hrow + k0 + j * 4);
            Hs[j * 4 + 0][tid] = hv.x;
            Hs[j * 4 + 1][tid] = hv.y;
            Hs[j * 4 + 2][tid] = hv.z;
            Hs[j * 4 + 3][tid] = hv.w;
        }
#pragma unroll
        for (int idx = 0; idx < BK * G / 256; ++idx) {
            int ii = tid + idx * 256;
            int k = ii / G, c = ii % G;
            float wv;
            if (m == 0) wv = W0[(size_t)(k0 + k) * G + c] - W2[(size_t)(k0 + k) * G + c];
            else wv = Wm[(size_t)(k0 + k) * G + c];
            Ws[k][c] = wv;
        }
        __syncthreads();
#pragma unroll
        for (int kk = 0; kk < BK; ++kk) {
            float4 ha = *(const float4*)&Hs[kk][rg * 4];
            float4 hb = *(const float4*)&Hs[kk][128 + rg * 4];
            float h[8] = {ha.x, ha.y, ha.z, ha.w, hb.x, hb.y, hb.z, hb.w};
            float w[CPT];
            if constexpr (CPT >= 4) {
#pragma unroll
                for (int c4 = 0; c4 < CPT / 4; ++c4) {
                    float4 wv = *(const float4*)&Ws[kk][c0 + c4 * 4];
                    w[c4 * 4 + 0] = wv.x;
                    w[c4 * 4 + 1] = wv.y;
                    w[c4 * 4 + 2] = wv.z;
                    w[c4 * 4 + 3] = wv.w;
                }
            } else {
                float2 wv = *(const float2*)&Ws[kk][c0];
                w[0] = wv.x;
                w[1] = wv.y;
            }
#pragma unroll
            for (int i = 0; i < 8; ++i)
#pragma unroll
                for (int c = 0; c < CPT; ++c) acc[i][c] = fmaf(h[i], w[c], acc[i][c]);
        }
        __syncthreads();
    }
#pragma unroll
    for (int half = 0; half < 2; ++half) {
#pragma unroll
        for (int i = 0; i < 4; ++i) {
            int r = rowBase + half * 128 + rg * 4 + i;
            if (r >= n) continue;
            int ai = half * 4 + i;
            if (m == 2) {
                ushort_t* dstp = C16 + (size_t)r * G + c0;
                if constexpr (CPT >= 4) {
#pragma unroll
                    for (int c4 = 0; c4 < CPT / 4; ++c4) {
                        ushort4 o;
                        o.x = f2bf(acc[ai][c4 * 4 + 0]);
                        o.y = f2bf(acc[ai][c4 * 4 + 1]);
                        o.z = f2bf(acc[ai][c4 * 4 + 2]);
                        o.w = f2bf(acc[ai][c4 * 4 + 3]);
                        *(ushort4*)(dstp + c4 * 4) = o;
                    }
                } else {
                    unsigned o = (unsigned)f2bf(acc[ai][0]) | ((unsigned)f2bf(acc[ai][1]) << 16);
                    *(unsigned*)dstp = o;
                }
            } else {
                float* dstp = (m == 0 ? YA : YB) + (size_t)r * G + c0;
                if constexpr (CPT >= 4) {
#pragma unroll
                    for (int c4 = 0; c4 < CPT / 4; ++c4) {
                        float4 o;
                        o.x = acc[ai][c4 * 4 + 0];
                        o.y = acc[ai][c4 * 4 + 1];
                        o.z = acc[ai][c4 * 4 + 2];
                        o.w = acc[ai][c4 * 4 + 3];
                        *(float4*)(dstp + c4 * 4) = o;
                    }
                } else {
                    float2 o;
                    o.x = acc[ai][0];
                    o.y = acc[ai][1];
                    *(float2*)dstp = o;
                }
            }
        }
    }
}

// ---------------- spmm with bf16 gather ----------------
// MODE 1: outS16[row] = bf16(Yres[row] - 2*(A@Hg)[row])
// MODE 2: outH[row] = relu(Yres[row] - (A@Hg)[row] + bias)
template <int G, int MODE>
__global__ __launch_bounds__(256) void spmm_bf16(const ushort_t* __restrict__ Hg,
                                                 const float* __restrict__ Yres,
                                                 const float* __restrict__ bias,
                                                 ushort_t* __restrict__ outS,
                                                 float* __restrict__ outH,
                                                 const int2* __restrict__ cv,
                                                 const int* __restrict__ rp, int n) {
    constexpr int TPR = G / 4;
    constexpr int RPB = 256 / TPR;
    int row = blockIdx.x * RPB + threadIdx.x / TPR;
    if (row >= n) return;
    int g = (threadIdx.x % TPR) * 4;
    float a0 = 0.f, a1 = 0.f, a2 = 0.f, a3 = 0.f;
    int e1 = rp[row + 1];
    for (int e = rp[row]; e < e1; ++e) {
        int2 c = cv[e];
        float v = __int_as_float(c.y);
        ushort4 hv = *(const ushort4*)(Hg + (size_t)c.x * G + g);
        a0 = fmaf(v, bf2f(hv.x), a0);
        a1 = fmaf(v, bf2f(hv.y), a1);
        a2 = fmaf(v, bf2f(hv.z), a2);
        a3 = fmaf(v, bf2f(hv.w), a3);
    }
    float4 yv = *(const float4*)(Yres + (size_t)row * G + g);
    if (MODE == 1) {
        ushort4 o;
        o.x = f2bf(yv.x - 2.f * a0);
        o.y = f2bf(yv.y - 2.f * a1);
        o.z = f2bf(yv.z - 2.f * a2);
        o.w = f2bf(yv.w - 2.f * a3);
        *(ushort4*)(outS + (size_t)row * G + g) = o;
    } else {
        float4 o;
        o.x = fmaxf(yv.x - a0 + bias[g + 0], 0.f);
        o.y = fmaxf(yv.y - a1 + bias[g + 1], 0.f);
        o.z = fmaxf(yv.z - a2 + bias[g + 2], 0.f);
        o.w = fmaxf(yv.w - a3 + bias[g + 3], 0.f);
        *(float4*)(outH + (size_t)row * G + g) = o;
    }
}

// ---------------- layer 4 (fp32 throughout; gather targets are L2-resident) ----------------

__global__ void gemm4(const float* __restrict__ H, const float* __restrict__ W,
                      float* __restrict__ YA, float* __restrict__ YB, float* __restrict__ C,
                      int n) {
    __shared__ float Ws[3 * 16 * 4];
    if (threadIdx.x < 192) Ws[threadIdx.x] = W[threadIdx.x];
    __syncthreads();
    int i = blockIdx.x * blockDim.x + threadIdx.x;
    if (i >= n) return;
    const float* h = H + (size_t)i * 16;
    float a[4], b[4], c[4];
#pragma unroll
    for (int g = 0; g < 4; ++g) a[g] = b[g] = c[g] = 0.f;
#pragma unroll
    for (int j = 0; j < 4; ++j) {
        float4 hv = *(const float4*)(h + j * 4);
        float hf[4] = {hv.x, hv.y, hv.z, hv.w};
#pragma unroll
        for (int k = 0; k < 4; ++k) {
            int f = j * 4 + k;
#pragma unroll
            for (int g = 0; g < 4; ++g) {
                a[g] = fmaf(hf[k], Ws[f * 4 + g], a[g]);
                b[g] = fmaf(hf[k], Ws[64 + f * 4 + g], b[g]);
                c[g] = fmaf(hf[k], Ws[128 + f * 4 + g], c[g]);
            }
        }
    }
    float4 oa, ob, oc;
    oa.x = a[0] - c[0]; oa.y = a[1] - c[1]; oa.z = a[2] - c[2]; oa.w = a[3] - c[3];
    ob.x = b[0]; ob.y = b[1]; ob.z = b[2]; ob.w = b[3];
    oc.x = c[0]; oc.y = c[1]; oc.z = c[2]; oc.w = c[3];
    *(float4*)(YA + (size_t)i * 4) = oa;
    *(float4*)(YB + (size_t)i * 4) = ob;
    *(float4*)(C + (size_t)i * 4) = oc;
}

__global__ void spmm4(const float* __restrict__ C, const float* __restrict__ YB,
                      float* __restrict__ S, const int2* __restrict__ cv,
                      const int* __restrict__ rp, int n) {
    int row = blockIdx.x * blockDim.x + threadIdx.x;
    if (row >= n) return;
    float a0 = 0.f, a1 = 0.f, a2 = 0.f, a3 = 0.f;
    int e1 = rp[row + 1];
    for (int e = rp[row]; e < e1; ++e) {
        int2 c = cv[e];
        float v = __int_as_float(c.y);
        float4 cvv = *(const float4*)(C + (size_t)c.x * 4);
        a0 = fmaf(v, cvv.x, a0);
        a1 = fmaf(v, cvv.y, a1);
        a2 = fmaf(v, cvv.z, a2);
        a3 = fmaf(v, cvv.w, a3);
    }
    float4 yb = *(const float4*)(YB + (size_t)row * 4);
    float4 o;
    o.x = yb.x - 2.f * a0;
    o.y = yb.y - 2.f * a1;
    o.z = yb.z - 2.f * a2;
    o.w = yb.w - 2.f * a3;
    *(float4*)(S + (size_t)row * 4) = o;
}

__global__ void layer4_final(const float* __restrict__ S, const float* __restrict__ YA,
                             const float* __restrict__ b, float* __restrict__ out,
                             const int2* __restrict__ cv, const int* __restrict__ rp, int n) {
    int row = blockIdx.x * blockDim.x + threadIdx.x;
    if (row >= n) return;
    float a0 = 0.f, a1 = 0.f, a2 = 0.f, a3 = 0.f;
    int e1 = rp[row + 1];
    for (int e = rp[row]; e < e1; ++e) {
        int2 c = cv[e];
        float v = __int_as_float(c.y);
        float4 sv = *(const float4*)(S + (size_t)c.x * 4);
        a0 = fmaf(v, sv.x, a0);
        a1 = fmaf(v, sv.y, a1);
        a2 = fmaf(v, sv.z, a2);
        a3 = fmaf(v, sv.w, a3);
    }
    float4 ya = *(const float4*)(YA + (size_t)row * 4);
    float o0 = ya.x - a0 + b[0];
    float o1 = ya.y - a1 + b[1];
    float o2 = ya.z - a2 + b[2];
    float o3 = ya.w - a3 + b[3];
    float m = fmaxf(fmaxf(o0, o1), fmaxf(o2, o3));
    float s = expf(o0 - m) + expf(o1 - m) + expf(o2 - m) + expf(o3 - m);
    float ls = m + logf(s);
    float4 r;
    r.x = o0 - ls;
    r.y = o1 - ls;
    r.z = o2 - ls;
    r.w = o3 - ls;
    *(float4*)(out + (size_t)row * 4) = r;
}

// ---------------- launch ----------------

static inline char* align_up(char* p, size_t a) {
    return (char*)(((uintptr_t)p + a - 1) & ~(uintptr_t)(a - 1));
}

extern "C" void kernel_launch(void* const* d_in, const int* in_sizes, int n_in,
                              void* d_out, int out_size, void* d_ws, size_t ws_size,
                              hipStream_t stream) {
    const float* x = (const float*)d_in[0];
    const int* ei = (const int*)d_in[1];
    const float* ew = (const float*)d_in[2];
    const float* W1 = (const float*)d_in[3];
    const float* b1 = (const float*)d_in[4];
    const float* W2 = (const float*)d_in[5];
    const float* b2 = (const float*)d_in[6];
    const float* W3 = (const float*)d_in[7];
    const float* b3 = (const float*)d_in[8];
    const float* W4 = (const float*)d_in[9];
    const float* b4 = (const float*)d_in[10];
    float* out = (float*)d_out;

    const int n = in_sizes[0] / D_IN;  // 100000
    const int E = in_sizes[2];         // 1600000
    const int* src = ei;
    const int* dst = ei + E;

    char* p = (char*)d_ws;
    int2* cv = (int2*)p;       p += (size_t)E * 8;
    float* deg = (float*)p;    p += (size_t)n * 4;
    int* cnt = (int*)p;        p += (size_t)n * 4;
    int* rp = (int*)p;         p = align_up(p + (size_t)(n + 1) * 4, 64);
    int* bsum = (int*)p;       p = align_up(p + 512, 64);
    float* YA = (float*)p;     p = align_up(p + (size_t)n * 64 * 4, 64);
    float* YB = (float*)p;     p = align_up(p + (size_t)n * 64 * 4, 64);
    ushort_t* C16 = (ushort_t*)p; p = align_up(p + (size_t)n * 64 * 2, 64);
    ushort_t* S16 = (ushort_t*)p; p = align_up(p + (size_t)n * 64 * 2, 64);
    float* H1 = (float*)p;     p = align_up(p + (size_t)n * 64 * 4, 64);
    float* H2 = (float*)p;     p = align_up(p + (size_t)n * 32 * 4, 64);
    float* H3 = (float*)p;     p = align_up(p + (size_t)n * 16 * 4, 64);
    float* YA4 = (float*)p;    p = align_up(p + (size_t)n * 4 * 4, 64);
    float* YB4 = (float*)p;    p = align_up(p + (size_t)n * 4 * 4, 64);
    float* C4 = (float*)p;     p = align_up(p + (size_t)n * 4 * 4, 64);
    float* S4 = (float*)p;     p = align_up(p + (size_t)n * 4 * 4, 64);

    const int TB = 256;
    int eb = (E + TB - 1) / TB;
    int nb256 = (n + TB - 1) / TB;
    int nscan = (n + 1023) / 1024;

    hipMemsetAsync(deg, 0, (size_t)n * 4, stream);
    hipMemsetAsync(cnt, 0, (size_t)n * 4, stream);
    deg_count_kernel<<<eb, TB, 0, stream>>>(src, dst, ew, deg, cnt, E);
    dinv_kernel<<<nb256, TB, 0, stream>>>(deg, n);
    scan1_kernel<<<nscan, 256, 0, stream>>>(cnt, rp + 1, bsum, n);
    scan2_kernel<<<1, 128, 0, stream>>>(bsum, nscan);
    scan3_kernel<<<nscan, 256, 0, stream>>>(rp + 1, bsum, n, rp);
    hipMemsetAsync(cnt, 0, (size_t)n * 4, stream);
    scatter_kernel<<<eb, TB, 0, stream>>>(src, dst, ew, deg, rp, cnt, cv, E);

    // ---- layer 1: F=128, G=64 ----
    {
        constexpr int F = 128, G = 64;
        dim3 gg((n + 255) / 256, 3);
        gemm3<F, G><<<gg, 256, 0, stream>>>(x, W1, YA, YB, C16, n);
        int sb = (n + (1024 / G) - 1) / (1024 / G);
        spmm_bf16<G, 1><<<sb, 256, 0, stream>>>(C16, YB, nullptr, S16, nullptr, cv, rp, n);
        spmm_bf16<G, 2><<<sb, 256, 0, stream>>>(S16, YA, b1, nullptr, H1, cv, rp, n);
    }
    // ---- layer 2: F=64, G=32 ----
    {
        constexpr int F = 64, G = 32;
        dim3 gg((n + 255) / 256, 3);
        gemm3<F, G><<<gg, 256, 0, stream>>>(H1, W2, YA, YB, C16, n);
        int sb = (n + (1024 / G) - 1) / (1024 / G);
        spmm_bf16<G, 1><<<sb, 256, 0, stream>>>(C16, YB, nullptr, S16, nullptr, cv, rp, n);
        spmm_bf16<G, 2><<<sb, 256, 0, stream>>>(S16, YA, b2, nullptr, H2, cv, rp, n);
    }
    // ---- layer 3: F=32, G=16 ----
    {
        constexpr int F = 32, G = 16;
        dim3 gg((n + 255) / 256, 3);
        gemm3<F, G><<<gg, 256, 0, stream>>>(H2, W3, YA, YB, C16, n);
        int sb = (n + (1024 / G) - 1) / (1024 / G);
        spmm_bf16<G, 1><<<sb, 256, 0, stream>>>(C16, YB, nullptr, S16, nullptr, cv, rp, n);
        spmm_bf16<G, 2><<<sb, 256, 0, stream>>>(S16, YA, b3, nullptr, H3, cv, rp, n);
    }
    // ---- layer 4: F=16, G=4 (fp32) ----
    {
        gemm4<<<nb256, 256, 0, stream>>>(H3, W4, YA4, YB4, C4, n);
        spmm4<<<nb256, 256, 0, stream>>>(C4, YB4, S4, cv, rp, n);
        layer4_final<<<nb256, 256, 0, stream>>>(S4, YA4, b4, out, cv, rp, n);
    }
}